// Round 7
// baseline (311.251 us; speedup 1.0000x reference)
//
#include <hip/hip_runtime.h>
#include <math.h>

#define LEAKY 0.2f
#define SB 256

typedef _Float16 half2v __attribute__((ext_vector_type(2)));
typedef _Float16 half4 __attribute__((ext_vector_type(4)));
typedef _Float16 half8 __attribute__((ext_vector_type(8)));
typedef float f32x4 __attribute__((ext_vector_type(4)));

static inline int ceil_div(int a, int b) { return (a + b - 1) / b; }

// storage index p -> original column, for 64-col groups (p<256 or p<64)
__device__ __forceinline__ int PERM(int p) {
  int q = p & 63;
  return (p & ~63) | (((q & 3) << 4) | (q >> 2));
}

// ---------------- CSR build ----------------
__global__ __launch_bounds__(256) void k_count(const int* __restrict__ ei,
                                               int* __restrict__ deg, int NE, int N) {
  int e = blockIdx.x * 256 + threadIdx.x;
  int ET = NE + N;
  if (e >= ET) return;
  int d = (e < NE) ? ei[NE + e] : (e - NE);
  atomicAdd(&deg[d], 1);
}

__global__ __launch_bounds__(256) void k_bsum(const int* __restrict__ deg,
                                              int* __restrict__ bsum, int N) {
  int b = blockIdx.x;
  int chunk = (N + SB - 1) / SB;
  int s0 = b * chunk, s1 = min(s0 + chunk, N);
  int t = threadIdx.x;
  int sum = 0;
  for (int i = s0 + t; i < s1; i += 256) sum += deg[i];
#pragma unroll
  for (int o = 32; o; o >>= 1) sum += __shfl_xor(sum, o, 64);
  __shared__ int red[4];
  if ((t & 63) == 0) red[t >> 6] = sum;
  __syncthreads();
  if (t == 0) bsum[b] = red[0] + red[1] + red[2] + red[3];
}

__global__ __launch_bounds__(256) void k_bscan(const int* __restrict__ bsum,
                                               int* __restrict__ bpre,
                                               int* __restrict__ off, int N) {
  __shared__ int s[256];
  int t = threadIdx.x;
  int v = bsum[t];
  s[t] = v;
  __syncthreads();
  for (int o = 1; o < 256; o <<= 1) {
    int u = (t >= o) ? s[t - o] : 0;
    __syncthreads();
    s[t] += u;
    __syncthreads();
  }
  bpre[t] = s[t] - v;
  if (t == 255) off[N] = s[255];
}

__global__ __launch_bounds__(256) void k_cscan(const int* __restrict__ deg,
                                               const int* __restrict__ bpre,
                                               int* __restrict__ off,
                                               int* __restrict__ cursor, int N) {
  int b = blockIdx.x;
  int chunk = (N + SB - 1) / SB;
  int i = b * chunk + threadIdx.x;
  int t = threadIdx.x;
  int valid = (t < chunk && i < N);
  int v = valid ? deg[i] : 0;
  __shared__ int s[256];
  s[t] = v;
  __syncthreads();
  for (int o = 1; o < 256; o <<= 1) {
    int u = (t >= o) ? s[t - o] : 0;
    __syncthreads();
    s[t] += u;
    __syncthreads();
  }
  if (valid) {
    int ex = s[t] - v + bpre[b];
    off[i] = ex;
    cursor[i] = ex;
  }
}

__global__ __launch_bounds__(256) void k_fill(const int* __restrict__ ei,
                                              int* __restrict__ cursor,
                                              int* __restrict__ csr, int NE, int N) {
  int e = blockIdx.x * 256 + threadIdx.x;
  int ET = NE + N;
  if (e >= ET) return;
  int s = (e < NE) ? ei[e] : (e - NE);
  int d = (e < NE) ? ei[NE + e] : (e - NE);
  int pos = atomicAdd(&cursor[d], 1);
  csr[pos] = s;
}

// ---------------- prep: weight fragments + folded attention vectors ---------
// w1hf[h][ks][ct][l][i] = W1[k][h*64+16ct+(l&15)], k=32ks+8(l>>4)+i  (h<4,ks<4,ct<4)
// w2f[ks][ct][l][i]     = W2[PERM(k')][16ct+(l&15)], k'=32ks+8(l>>4)+i (ks<8,ct<4)
// wt1s/wt1d[k*4+h] = sum_d W1[k][h*64+d]*a1[h][d]
// wt2sp/wt2dp[p]   = sum_d W2[PERM(p)][d]*a2[d]
// b1p[p] = b1[PERM(p)]
__global__ __launch_bounds__(256) void k_prep(const float* __restrict__ W1,
                                              const float* __restrict__ W2,
                                              const float* __restrict__ a_src1,
                                              const float* __restrict__ a_dst1,
                                              const float* __restrict__ a_src2,
                                              const float* __restrict__ a_dst2,
                                              const float* __restrict__ b1,
                                              _Float16* __restrict__ w1hf,
                                              _Float16* __restrict__ w2f,
                                              float* __restrict__ wt1s,
                                              float* __restrict__ wt1d,
                                              float* __restrict__ wt2sp,
                                              float* __restrict__ wt2dp,
                                              float* __restrict__ b1p) {
  int idx = blockIdx.x * 256 + threadIdx.x;
  if (idx < 32768) {  // w1hf
    int i = idx & 7, l = (idx >> 3) & 63, ct = (idx >> 9) & 3, ks = (idx >> 11) & 3,
        h = idx >> 13;
    int k = 32 * ks + 8 * (l >> 4) + i;
    int col = h * 64 + 16 * ct + (l & 15);
    w1hf[idx] = (_Float16)W1[k * 256 + col];
    return;
  }
  int i2 = idx - 32768;
  if (i2 < 16384) {  // w2f
    int i = i2 & 7, l = (i2 >> 3) & 63, ct = (i2 >> 9) & 3, ks = i2 >> 11;
    int kp = 32 * ks + 8 * (l >> 4) + i;
    int col = 16 * ct + (l & 15);
    w2f[i2] = (_Float16)W2[PERM(kp) * 64 + col];
    return;
  }
  int i3 = i2 - 16384;
  if (i3 < 512) {  // wt1 (k<128, h<4)
    int h = i3 & 3, k = i3 >> 2;
    float ss = 0.f, sd = 0.f;
    for (int d = 0; d < 64; ++d) {
      float wv = W1[k * 256 + h * 64 + d];
      ss = fmaf(wv, a_src1[h * 64 + d], ss);
      sd = fmaf(wv, a_dst1[h * 64 + d], sd);
    }
    wt1s[i3] = ss;
    wt1d[i3] = sd;
    return;
  }
  int i4 = i3 - 512;
  if (i4 < 256) {  // wt2p
    int ko = PERM(i4);
    float ss = 0.f, sd = 0.f;
    for (int d = 0; d < 64; ++d) {
      float wv = W2[ko * 64 + d];
      ss = fmaf(wv, a_src2[d], ss);
      sd = fmaf(wv, a_dst2[d], sd);
    }
    wt2sp[i4] = ss;
    wt2dp[i4] = sd;
    return;
  }
  int i5 = i4 - 256;
  if (i5 < 256) b1p[i5] = b1[PERM(i5)];
}

// ---------------- logits1: as1/ad1 = x @ wt1, also emit x16 -----------------
// wave per node; lane covers k = 2l, 2l+1
__global__ __launch_bounds__(256) void k_logits1(const float* __restrict__ x,
                                                 const float* __restrict__ wt1s,
                                                 const float* __restrict__ wt1d,
                                                 _Float16* __restrict__ x16,
                                                 float* __restrict__ as1,
                                                 float* __restrict__ ad1, int N) {
  int w = threadIdx.x >> 6, l = threadIdx.x & 63;
  int n = blockIdx.x * 4 + w;
  if (n >= N) return;
  float2 xv = *reinterpret_cast<const float2*>(x + (size_t)n * 128 + 2 * l);
  half2v xh;
  xh[0] = (_Float16)xv.x;
  xh[1] = (_Float16)xv.y;
  *reinterpret_cast<half2v*>(x16 + (size_t)n * 128 + 2 * l) = xh;
  float4 w0s = reinterpret_cast<const float4*>(wt1s)[2 * l];
  float4 w1s = reinterpret_cast<const float4*>(wt1s)[2 * l + 1];
  float4 w0d = reinterpret_cast<const float4*>(wt1d)[2 * l];
  float4 w1d = reinterpret_cast<const float4*>(wt1d)[2 * l + 1];
  float sa[4], sd[4];
  sa[0] = xv.x * w0s.x + xv.y * w1s.x;
  sa[1] = xv.x * w0s.y + xv.y * w1s.y;
  sa[2] = xv.x * w0s.z + xv.y * w1s.z;
  sa[3] = xv.x * w0s.w + xv.y * w1s.w;
  sd[0] = xv.x * w0d.x + xv.y * w1d.x;
  sd[1] = xv.x * w0d.y + xv.y * w1d.y;
  sd[2] = xv.x * w0d.z + xv.y * w1d.z;
  sd[3] = xv.x * w0d.w + xv.y * w1d.w;
#pragma unroll
  for (int o = 1; o <= 32; o <<= 1) {
#pragma unroll
    for (int h = 0; h < 4; ++h) {
      sa[h] += __shfl_xor(sa[h], o, 64);
      sd[h] += __shfl_xor(sd[h], o, 64);
    }
  }
  if (l == 0) {
#pragma unroll
    for (int h = 0; h < 4; ++h) {
      as1[n * 4 + h] = sa[h];
      ad1[n * 4 + h] = sd[h];
    }
  }
}

// ---------------- alpha precompute, layer 1 (H=4) ----------------
__global__ __launch_bounds__(256) void k_alpha1(const float* __restrict__ as1,
                                                const float* __restrict__ ad1,
                                                const int* __restrict__ off,
                                                const int* __restrict__ csr,
                                                float* __restrict__ alpha, int N) {
  int w = threadIdx.x >> 6, lane = threadIdx.x & 63;
  int n = blockIdx.x * 4 + w;
  if (n >= N) return;
  int eidx = lane >> 2, h = lane & 3;
  float adv = ad1[n * 4 + h];
  int e0 = off[n], e1 = off[n + 1];
  float m = -INFINITY;
  for (int base = e0; base < e1; base += 16) {
    int idx = base + eidx;
    if (idx < e1) {
      int s = csr[idx];
      float t = as1[s * 4 + h] + adv;
      t = t > 0.f ? t : LEAKY * t;
      m = fmaxf(m, t);
    }
  }
#pragma unroll
  for (int o = 4; o <= 32; o <<= 1) m = fmaxf(m, __shfl_xor(m, o, 64));
  float lp = 0.f;
  for (int base = e0; base < e1; base += 16) {
    int idx = base + eidx;
    if (idx < e1) {
      int s = csr[idx];
      float t = as1[s * 4 + h] + adv;
      t = t > 0.f ? t : LEAKY * t;
      float p = __expf(t - m);
      alpha[(size_t)idx * 4 + h] = p;
      lp += p;
    }
  }
#pragma unroll
  for (int o = 4; o <= 32; o <<= 1) lp += __shfl_xor(lp, o, 64);
  float rinv = 1.f / lp;
  for (int base = e0; base < e1; base += 16) {
    int idx = base + eidx;
    if (idx < e1) alpha[(size_t)idx * 4 + h] *= rinv;
  }
}

// ---------------- fused layer-1: aggregate x16 per head, then block-diag MFMA
// block = 512 thr (8 waves), 64 nodes. LDS xagg[node][h*128+k] fp16, XOR-swizzled.
// hout1p[n][p] = ReLU(xagg_h @ W1_h + b1)[PERM(p)],  p = h*64 + lrow*4 + ct
__global__ __launch_bounds__(512) void k_fagg1(const _Float16* __restrict__ x16,
                                               const float* __restrict__ alpha,
                                               const _Float16* __restrict__ w1hf,
                                               const float* __restrict__ b1p,
                                               const int* __restrict__ off,
                                               const int* __restrict__ csr,
                                               _Float16* __restrict__ hout1p, int N) {
  __shared__ _Float16 xs[64 * 512];  // 64 KiB
  int w = threadIdx.x >> 6, l = threadIdx.x & 63;
  int node0 = blockIdx.x * 64;
  // ---- phase 1: each wave aggregates 8 nodes; lane covers k = 2l, 2l+1 ----
  for (int s = 0; s < 8; ++s) {
    int nn = w * 8 + s;
    int n = node0 + nn;
    float acc[4][2] = {{0.f, 0.f}, {0.f, 0.f}, {0.f, 0.f}, {0.f, 0.f}};
    if (n < N) {
      int e0 = off[n], e1 = off[n + 1];
      for (int base = e0; base < e1; base += 4) {
#pragma unroll
        for (int u = 0; u < 4; ++u) {
          int e = base + u;
          int ec = min(e, e1 - 1);
          int src = csr[ec];
          float4 al = *reinterpret_cast<const float4*>(alpha + (size_t)ec * 4);
          if (e >= e1) al = make_float4(0.f, 0.f, 0.f, 0.f);
          half2v hv = *reinterpret_cast<const half2v*>(x16 + (size_t)src * 128 + 2 * l);
          float h0 = (float)hv[0], h1 = (float)hv[1];
          acc[0][0] = fmaf(al.x, h0, acc[0][0]);
          acc[0][1] = fmaf(al.x, h1, acc[0][1]);
          acc[1][0] = fmaf(al.y, h0, acc[1][0]);
          acc[1][1] = fmaf(al.y, h1, acc[1][1]);
          acc[2][0] = fmaf(al.z, h0, acc[2][0]);
          acc[2][1] = fmaf(al.z, h1, acc[2][1]);
          acc[3][0] = fmaf(al.w, h0, acc[3][0]);
          acc[3][1] = fmaf(al.w, h1, acc[3][1]);
        }
      }
    }
    int swz = (nn & 7) << 3;
#pragma unroll
    for (int h = 0; h < 4; ++h) {
      half2v o;
      o[0] = (_Float16)acc[h][0];
      o[1] = (_Float16)acc[h][1];
      *reinterpret_cast<half2v*>(&xs[nn * 512 + ((h * 128 + 2 * l) ^ swz)]) = o;
    }
  }
  __syncthreads();
  // ---- phase 2: block-diagonal MFMA. wave w -> m-tile (w&3), heads 2*(w>>2)+hi
  int mt = w & 3, lrow = l & 15, lgrp = l >> 4;
  int nodeA = 16 * mt + lrow;         // A-fragment row
  int swzA = (nodeA & 7) << 3;
#pragma unroll
  for (int hi = 0; hi < 2; ++hi) {
    int h = (w >> 2) * 2 + hi;
    f32x4 acc[4];
#pragma unroll
    for (int ct = 0; ct < 4; ++ct) acc[ct] = (f32x4){0.f, 0.f, 0.f, 0.f};
#pragma unroll
    for (int ks = 0; ks < 4; ++ks) {
      half8 af = *reinterpret_cast<const half8*>(
          &xs[nodeA * 512 + ((h * 128 + 32 * ks + 8 * lgrp) ^ swzA)]);
      const half8* bp =
          reinterpret_cast<const half8*>(w1hf) + (size_t)((h * 4 + ks) * 4) * 64 + l;
#pragma unroll
      for (int ct = 0; ct < 4; ++ct) {
        half8 bf = bp[ct * 64];
        acc[ct] = __builtin_amdgcn_mfma_f32_16x16x32_f16(af, bf, acc[ct], 0, 0, 0);
      }
    }
    float4 bv = *reinterpret_cast<const float4*>(b1p + h * 64 + lrow * 4);
    int rbase = node0 + 16 * mt + 4 * lgrp;
#pragma unroll
    for (int r = 0; r < 4; ++r) {
      int n = rbase + r;
      if (n < N) {
        half4 o;
        o[0] = (_Float16)fmaxf(acc[0][r] + bv.x, 0.f);
        o[1] = (_Float16)fmaxf(acc[1][r] + bv.y, 0.f);
        o[2] = (_Float16)fmaxf(acc[2][r] + bv.z, 0.f);
        o[3] = (_Float16)fmaxf(acc[3][r] + bv.w, 0.f);
        *reinterpret_cast<half4*>(hout1p + (size_t)n * 256 + h * 64 + lrow * 4) = o;
      }
    }
  }
}

// ---------------- logits2: as2/ad2 = hout1p @ wt2p ----------------
__global__ __launch_bounds__(256) void k_logits2(const _Float16* __restrict__ hout1p,
                                                 const float* __restrict__ wt2sp,
                                                 const float* __restrict__ wt2dp,
                                                 float* __restrict__ as2,
                                                 float* __restrict__ ad2, int N) {
  int w = threadIdx.x >> 6, l = threadIdx.x & 63;
  int n = blockIdx.x * 4 + w;
  if (n >= N) return;
  half4 hv = *reinterpret_cast<const half4*>(hout1p + (size_t)n * 256 + 4 * l);
  float4 ws = reinterpret_cast<const float4*>(wt2sp)[l];
  float4 wd = reinterpret_cast<const float4*>(wt2dp)[l];
  float h0 = (float)hv[0], h1 = (float)hv[1], h2 = (float)hv[2], h3 = (float)hv[3];
  float sa = h0 * ws.x + h1 * ws.y + h2 * ws.z + h3 * ws.w;
  float sd = h0 * wd.x + h1 * wd.y + h2 * wd.z + h3 * wd.w;
#pragma unroll
  for (int o = 1; o <= 32; o <<= 1) {
    sa += __shfl_xor(sa, o, 64);
    sd += __shfl_xor(sd, o, 64);
  }
  if (l == 0) {
    as2[n] = sa;
    ad2[n] = sd;
  }
}

// ---------------- alpha precompute, layer 2 (H=1) ----------------
__global__ __launch_bounds__(256) void k_alpha2(const float* __restrict__ as2,
                                                const float* __restrict__ ad2,
                                                const int* __restrict__ off,
                                                const int* __restrict__ csr,
                                                float* __restrict__ alpha, int N) {
  int w = threadIdx.x >> 6, lane = threadIdx.x & 63;
  int n = blockIdx.x * 4 + w;
  if (n >= N) return;
  float adv = ad2[n];
  int e0 = off[n], e1 = off[n + 1];
  float m = -INFINITY;
  for (int base = e0; base < e1; base += 64) {
    int idx = base + lane;
    if (idx < e1) {
      float t = as2[csr[idx]] + adv;
      t = t > 0.f ? t : LEAKY * t;
      m = fmaxf(m, t);
    }
  }
#pragma unroll
  for (int o = 1; o <= 32; o <<= 1) m = fmaxf(m, __shfl_xor(m, o, 64));
  float lp = 0.f;
  for (int base = e0; base < e1; base += 64) {
    int idx = base + lane;
    if (idx < e1) {
      float t = as2[csr[idx]] + adv;
      t = t > 0.f ? t : LEAKY * t;
      float p = __expf(t - m);
      alpha[idx] = p;
      lp += p;
    }
  }
#pragma unroll
  for (int o = 1; o <= 32; o <<= 1) lp += __shfl_xor(lp, o, 64);
  float rinv = 1.f / lp;
  for (int base = e0; base < e1; base += 64) {
    int idx = base + lane;
    if (idx < e1) alpha[idx] *= rinv;
  }
}

// ---------------- Layer 2 GEMM (MFMA): h2p = hout1p @ w2f (permuted store) ---
__global__ __launch_bounds__(256) void k_gemm2(const _Float16* __restrict__ hin,
                                               const _Float16* __restrict__ w2f,
                                               _Float16* __restrict__ h2p, int N) {
  int w = threadIdx.x >> 6, l = threadIdx.x & 63;
  int n0 = blockIdx.x * 64 + 16 * w;
  int lrow = l & 15, lgrp = l >> 4;
  int arow = min(n0 + lrow, N - 1);
  f32x4 acc[4];
#pragma unroll
  for (int ct = 0; ct < 4; ++ct) acc[ct] = (f32x4){0.f, 0.f, 0.f, 0.f};
#pragma unroll
  for (int ks = 0; ks < 8; ++ks) {
    half8 af =
        *reinterpret_cast<const half8*>(hin + (size_t)arow * 256 + 32 * ks + 8 * lgrp);
    const half8* bp = reinterpret_cast<const half8*>(w2f) + (size_t)(ks * 4) * 64 + l;
#pragma unroll
    for (int ct = 0; ct < 4; ++ct) {
      half8 bf = bp[ct * 64];
      acc[ct] = __builtin_amdgcn_mfma_f32_16x16x32_f16(af, bf, acc[ct], 0, 0, 0);
    }
  }
  int rbase = n0 + 4 * lgrp;
#pragma unroll
  for (int r = 0; r < 4; ++r) {
    int row = rbase + r;
    if (row < N) {
      half4 o;
      o[0] = (_Float16)acc[0][r];
      o[1] = (_Float16)acc[1][r];
      o[2] = (_Float16)acc[2][r];
      o[3] = (_Float16)acc[3][r];
      *reinterpret_cast<half4*>(h2p + (size_t)row * 64 + lrow * 4) = o;
    }
  }
}

// ---------------- Layer 2 aggregation (reads permuted h2p, writes orig out) --
__global__ __launch_bounds__(256) void k_agg2(const _Float16* __restrict__ h2p,
                                              const float* __restrict__ alpha,
                                              const float* __restrict__ b2,
                                              const int* __restrict__ off,
                                              const int* __restrict__ csr,
                                              float* __restrict__ out, int N) {
  int w = threadIdx.x >> 6, lane = threadIdx.x & 63;
  int n = blockIdx.x * 4 + w;
  if (n >= N) return;
  int sub = lane >> 4, q = lane & 15;
  int e0 = off[n], e1 = off[n + 1];
  float4 acc = make_float4(0.f, 0.f, 0.f, 0.f);
  for (int base = e0; base < e1; base += 8) {
#pragma unroll
    for (int u = 0; u < 2; ++u) {
      int e = base + u * 4 + sub;
      int ec = min(e, e1 - 1);
      int s = csr[ec];
      float a = alpha[ec];
      if (e >= e1) a = 0.f;
      half4 hv = *reinterpret_cast<const half4*>(h2p + (size_t)s * 64 + 4 * q);
      acc.x = fmaf(a, (float)hv[0], acc.x);
      acc.y = fmaf(a, (float)hv[1], acc.y);
      acc.z = fmaf(a, (float)hv[2], acc.z);
      acc.w = fmaf(a, (float)hv[3], acc.w);
    }
  }
#pragma unroll
  for (int o = 16; o <= 32; o <<= 1) {
    acc.x += __shfl_xor(acc.x, o, 64);
    acc.y += __shfl_xor(acc.y, o, 64);
    acc.z += __shfl_xor(acc.z, o, 64);
    acc.w += __shfl_xor(acc.w, o, 64);
  }
  if (lane < 16) {
    // component j holds orig col 16*j + q
    out[(size_t)n * 64 + q] = acc.x + b2[q];
    out[(size_t)n * 64 + 16 + q] = acc.y + b2[16 + q];
    out[(size_t)n * 64 + 32 + q] = acc.z + b2[32 + q];
    out[(size_t)n * 64 + 48 + q] = acc.w + b2[48 + q];
  }
}

extern "C" void kernel_launch(void* const* d_in, const int* in_sizes, int n_in,
                              void* d_out, int out_size, void* d_ws, size_t ws_size,
                              hipStream_t stream) {
  const float* x = (const float*)d_in[0];
  const int* ei = (const int*)d_in[1];
  const float* W1 = (const float*)d_in[2];
  const float* a_src1 = (const float*)d_in[3];
  const float* a_dst1 = (const float*)d_in[4];
  const float* b1 = (const float*)d_in[5];
  const float* W2 = (const float*)d_in[6];
  const float* a_src2 = (const float*)d_in[7];
  const float* a_dst2 = (const float*)d_in[8];
  const float* b2 = (const float*)d_in[9];
  float* out = (float*)d_out;

  const int N = in_sizes[0] / 128;
  const int NE = in_sizes[1] / 2;
  const int ET = NE + N;

  char* p = (char*)d_ws;
  auto alloc = [&](size_t bytes) {
    char* r = p;
    p += (bytes + 255) & ~(size_t)255;
    return r;
  };
  int* deg = (int*)alloc((size_t)N * 4);
  int* cursor = (int*)alloc((size_t)N * 4);
  int* off = (int*)alloc((size_t)(N + 1) * 4);
  int* csr = (int*)alloc((size_t)ET * 4);
  int* bsum = (int*)alloc((size_t)SB * 4);
  int* bpre = (int*)alloc((size_t)SB * 4);
  _Float16* w1hf = (_Float16*)alloc((size_t)32768 * 2);
  _Float16* w2f = (_Float16*)alloc((size_t)16384 * 2);
  float* wt1s = (float*)alloc((size_t)512 * 4);
  float* wt1d = (float*)alloc((size_t)512 * 4);
  float* wt2sp = (float*)alloc((size_t)256 * 4);
  float* wt2dp = (float*)alloc((size_t)256 * 4);
  float* b1p = (float*)alloc((size_t)256 * 4);
  _Float16* x16 = (_Float16*)alloc((size_t)N * 128 * 2);
  _Float16* hout1p = (_Float16*)alloc((size_t)N * 256 * 2);
  float* as1 = (float*)alloc((size_t)N * 4 * 4);
  float* ad1 = (float*)alloc((size_t)N * 4 * 4);
  float* alpha1 = (float*)alloc((size_t)ET * 4 * 4);
  _Float16* h2p = x16;      // reuse: x16 dead after k_fagg1
  float* alpha2 = alpha1;   // reuse: alpha1 dead after k_fagg1
  float* as2 = (float*)alloc((size_t)N * 4);
  float* ad2 = (float*)alloc((size_t)N * 4);

  hipMemsetAsync(deg, 0, (size_t)N * 4, stream);
  k_count<<<ceil_div(ET, 256), 256, 0, stream>>>(ei, deg, NE, N);
  k_bsum<<<SB, 256, 0, stream>>>(deg, bsum, N);
  k_bscan<<<1, 256, 0, stream>>>(bsum, bpre, off, N);
  k_cscan<<<SB, 256, 0, stream>>>(deg, bpre, off, cursor, N);
  k_fill<<<ceil_div(ET, 256), 256, 0, stream>>>(ei, cursor, csr, NE, N);
  k_prep<<<198, 256, 0, stream>>>(W1, W2, a_src1, a_dst1, a_src2, a_dst2, b1,
                                  w1hf, w2f, wt1s, wt1d, wt2sp, wt2dp, b1p);

  k_logits1<<<ceil_div(N, 4), 256, 0, stream>>>(x, wt1s, wt1d, x16, as1, ad1, N);
  k_alpha1<<<ceil_div(N, 4), 256, 0, stream>>>(as1, ad1, off, csr, alpha1, N);
  k_fagg1<<<ceil_div(N, 64), 512, 0, stream>>>(x16, alpha1, w1hf, b1p, off, csr,
                                               hout1p, N);
  k_logits2<<<ceil_div(N, 4), 256, 0, stream>>>(hout1p, wt2sp, wt2dp, as2, ad2, N);
  k_alpha2<<<ceil_div(N, 4), 256, 0, stream>>>(as2, ad2, off, csr, alpha2, N);
  k_gemm2<<<ceil_div(N, 64), 256, 0, stream>>>(hout1p, w2f, h2p, N);
  k_agg2<<<ceil_div(N, 4), 256, 0, stream>>>(h2p, alpha2, b2, off, csr, out, N);
}